// Round 1
// baseline (360.825 us; speedup 1.0000x reference)
//
#include <hip/hip_runtime.h>
#include <hip/hip_bf16.h>

#define SEQ 240
#define HID 4096
#define NH 16
#define HD 256

typedef float f32x4 __attribute__((ext_vector_type(4)));
typedef short s16x8 __attribute__((ext_vector_type(8)));

__device__ __forceinline__ short f2bf(float f) {
    unsigned u = __builtin_bit_cast(unsigned, f);
    unsigned r = u + 0x7FFFu + ((u >> 16) & 1u);
    return (short)(r >> 16);
}

__device__ __forceinline__ s16x8 cvt8(float4 a, float4 b) {
    s16x8 r;
    r[0] = f2bf(a.x); r[1] = f2bf(a.y); r[2] = f2bf(a.z); r[3] = f2bf(a.w);
    r[4] = f2bf(b.x); r[5] = f2bf(b.y); r[6] = f2bf(b.z); r[7] = f2bf(b.w);
    return r;
}

// ---------------------------------------------------------------------------
// Kernel 1: fused QKV projection.  C = A @ W^T + b  (NT gemm, both K-contig)
// grid (4096/64, 3): y selects {q,k,v}.  BM=256 (240 padded), BN=64, BK=32.
// v output is stored TRANSPOSED (vt[n][m]) so the PV gemm is also NT.
// ---------------------------------------------------------------------------
__global__ __launch_bounds__(256) void qkv_kernel(
    const float* __restrict__ in1, const float* __restrict__ in2,
    const float* __restrict__ Wq, const float* __restrict__ bq,
    const float* __restrict__ Wk, const float* __restrict__ bk,
    const float* __restrict__ Wv, const float* __restrict__ bv,
    float* __restrict__ qbuf, float* __restrict__ kbuf, float* __restrict__ vtbuf)
{
    const int g = blockIdx.y;
    const float* __restrict__ A    = (g == 0) ? in1 : in2;
    const float* __restrict__ W    = (g == 0) ? Wq : (g == 1) ? Wk : Wv;
    const float* __restrict__ bias = (g == 0) ? bq : (g == 1) ? bk : bv;

    const int nb   = blockIdx.x * 64;
    const int tid  = threadIdx.x;
    const int lane = tid & 63;
    const int wave = tid >> 6;
    const int wr   = wave >> 1;   // m-half (0/1): rows wr*128..+127
    const int wc   = wave & 1;    // n-half (0/1): cols wc*32..+31
    const int lr   = lane & 15;
    const int lg   = lane >> 4;

    // pad rows to 40 shorts (80B, 16B-aligned, 2-way bank aliasing = free)
    __shared__ short As[256][40];
    __shared__ short Ws[64][40];

    f32x4 acc[8][2];
    #pragma unroll
    for (int m = 0; m < 8; ++m)
        #pragma unroll
        for (int n = 0; n < 2; ++n)
            acc[m][n] = (f32x4){0.f, 0.f, 0.f, 0.f};

    const int arow = tid >> 3;   // 0..31
    const int aseg = tid & 7;    // float4 segment within the 32-wide K slab

    for (int k0 = 0; k0 < HID; k0 += 32) {
        __syncthreads();
        // stage A tile (256 x 32 f32 -> bf16), rows >= 240 zeroed
        #pragma unroll
        for (int r = 0; r < 8; ++r) {
            int row = arow + r * 32;
            float4 v = make_float4(0.f, 0.f, 0.f, 0.f);
            if (row < SEQ) v = *(const float4*)&A[row * HID + k0 + aseg * 4];
            short* dst = &As[row][aseg * 4];
            dst[0] = f2bf(v.x); dst[1] = f2bf(v.y);
            dst[2] = f2bf(v.z); dst[3] = f2bf(v.w);
        }
        // stage W tile (64 x 32 f32 -> bf16)
        #pragma unroll
        for (int r = 0; r < 2; ++r) {
            int row = arow + r * 32;
            float4 v = *(const float4*)&W[(nb + row) * HID + k0 + aseg * 4];
            short* dst = &Ws[row][aseg * 4];
            dst[0] = f2bf(v.x); dst[1] = f2bf(v.y);
            dst[2] = f2bf(v.z); dst[3] = f2bf(v.w);
        }
        __syncthreads();

        s16x8 bfr0 = *(const s16x8*)&Ws[(wc*2 + 0)*16 + lr][lg * 8];
        s16x8 bfr1 = *(const s16x8*)&Ws[(wc*2 + 1)*16 + lr][lg * 8];
        #pragma unroll
        for (int m = 0; m < 8; ++m) {
            s16x8 afr = *(const s16x8*)&As[wr*128 + m*16 + lr][lg * 8];
            acc[m][0] = __builtin_amdgcn_mfma_f32_16x16x32_bf16(afr, bfr0, acc[m][0], 0, 0, 0);
            acc[m][1] = __builtin_amdgcn_mfma_f32_16x16x32_bf16(afr, bfr1, acc[m][1], 0, 0, 0);
        }
    }

    // epilogue: bias add + store (C/D map: col=lane&15, row=(lane>>4)*4+reg)
    #pragma unroll
    for (int n = 0; n < 2; ++n) {
        const int ncol = nb + (wc*2 + n)*16 + lr;
        const float bb = bias[ncol];
        #pragma unroll
        for (int m = 0; m < 8; ++m) {
            const int m0 = wr*128 + m*16 + lg*4;
            if (m0 >= SEQ) continue;
            if (g == 2) {
                // transposed store: vt[n][m], 4 consecutive m -> one float4
                float4 o = make_float4(acc[m][n][0] + bb, acc[m][n][1] + bb,
                                       acc[m][n][2] + bb, acc[m][n][3] + bb);
                *(float4*)&vtbuf[ncol * SEQ + m0] = o;
            } else {
                float* ob = (g == 0) ? qbuf : kbuf;
                #pragma unroll
                for (int r = 0; r < 4; ++r)
                    ob[(m0 + r) * HID + ncol] = acc[m][n][r] + bb;
            }
        }
    }
}

// ---------------------------------------------------------------------------
// Kernel 2: scores + row softmax.  S[i,j] = (Q_h K_h^T)/16, P stored
// TRANSPOSED: pt[h][j][i].  One wave per (16-row q-tile, head).
// ---------------------------------------------------------------------------
__global__ __launch_bounds__(64) void scores_kernel(
    const float* __restrict__ qbuf, const float* __restrict__ kbuf,
    float* __restrict__ pt)
{
    const int it   = blockIdx.x;     // 0..14
    const int h    = blockIdx.y;     // 0..15
    const int lane = threadIdx.x;
    const int lr   = lane & 15;
    const int lg   = lane >> 4;

    f32x4 acc[15];
    #pragma unroll
    for (int j = 0; j < 15; ++j) acc[j] = (f32x4){0.f, 0.f, 0.f, 0.f};

    const int ib = it * 16;
    const float* qrow = &qbuf[(ib + lr) * HID + h * HD + lg * 8];

    for (int d0 = 0; d0 < HD; d0 += 32) {
        float4 a0 = *(const float4*)&qrow[d0];
        float4 a1 = *(const float4*)&qrow[d0 + 4];
        s16x8 afr = cvt8(a0, a1);
        #pragma unroll
        for (int jt = 0; jt < 15; ++jt) {
            const float* krow = &kbuf[(jt*16 + lr) * HID + h * HD + d0 + lg * 8];
            float4 b0 = *(const float4*)&krow[0];
            float4 b1 = *(const float4*)&krow[4];
            acc[jt] = __builtin_amdgcn_mfma_f32_16x16x32_bf16(afr, cvt8(b0, b1), acc[jt], 0, 0, 0);
        }
    }

    const float sc = 0.0625f;  // 1/sqrt(256)
    #pragma unroll
    for (int jt = 0; jt < 15; ++jt) acc[jt] *= sc;

    // softmax over j: row r lives in the 16 lanes sharing lg, across 15 tiles
    #pragma unroll
    for (int r = 0; r < 4; ++r) {
        float mx = acc[0][r];
        #pragma unroll
        for (int jt = 1; jt < 15; ++jt) mx = fmaxf(mx, acc[jt][r]);
        #pragma unroll
        for (int s = 1; s < 16; s <<= 1) mx = fmaxf(mx, __shfl_xor(mx, s, 64));
        float sum = 0.f;
        #pragma unroll
        for (int jt = 0; jt < 15; ++jt) {
            float e = expf(acc[jt][r] - mx);
            acc[jt][r] = e;
            sum += e;
        }
        #pragma unroll
        for (int s = 1; s < 16; s <<= 1) sum += __shfl_xor(sum, s, 64);
        float inv = 1.f / sum;
        #pragma unroll
        for (int jt = 0; jt < 15; ++jt) acc[jt][r] *= inv;
    }

    // store P^T: pt[(h*240 + j)*240 + i]; 4 consecutive i -> float4
    #pragma unroll
    for (int jt = 0; jt < 15; ++jt) {
        const int j = jt*16 + lr;
        float4 o = make_float4(acc[jt][0], acc[jt][1], acc[jt][2], acc[jt][3]);
        *(float4*)&pt[(h*SEQ + j)*SEQ + ib + lg*4] = o;
    }
}

// ---------------------------------------------------------------------------
// Kernel 3: O = P^T V per head == pt (NT, K=i over 240 padded to 256) with
// vt as the B operand.  One wave per (16-wide d-tile, head).
// ---------------------------------------------------------------------------
__global__ __launch_bounds__(64) void pv_kernel(
    const float* __restrict__ pt, const float* __restrict__ vtbuf,
    float* __restrict__ out)
{
    const int dt   = blockIdx.x;     // 0..15
    const int h    = blockIdx.y;
    const int lane = threadIdx.x;
    const int lr   = lane & 15;
    const int lg   = lane >> 4;

    f32x4 acc[15];
    #pragma unroll
    for (int m = 0; m < 15; ++m) acc[m] = (f32x4){0.f, 0.f, 0.f, 0.f};

    const float* vrow  = &vtbuf[(h*HD + dt*16 + lr) * SEQ + lg*8];
    const float* pbase = &pt[h*SEQ*SEQ];

    for (int i0 = 0; i0 < 256; i0 += 32) {
        const bool ok = (i0 + lg*8) < SEQ;   // 240 % 8 == 0, clean mask
        s16x8 bfr = (s16x8){0,0,0,0,0,0,0,0};
        if (ok) {
            float4 b0 = *(const float4*)&vrow[i0];
            float4 b1 = *(const float4*)&vrow[i0 + 4];
            bfr = cvt8(b0, b1);
        }
        #pragma unroll
        for (int mt = 0; mt < 15; ++mt) {
            s16x8 afr = (s16x8){0,0,0,0,0,0,0,0};
            if (ok) {
                const float* prow = &pbase[(mt*16 + lr)*SEQ + i0 + lg*8];
                float4 a0 = *(const float4*)&prow[0];
                float4 a1 = *(const float4*)&prow[4];
                afr = cvt8(a0, a1);
            }
            acc[mt] = __builtin_amdgcn_mfma_f32_16x16x32_bf16(afr, bfr, acc[mt], 0, 0, 0);
        }
    }

    // out[j, h*256 + d]: col=lr is d (coalesced), rows j = mt*16 + lg*4 + r
    #pragma unroll
    for (int mt = 0; mt < 15; ++mt) {
        const int jb = mt*16 + lg*4;
        #pragma unroll
        for (int r = 0; r < 4; ++r)
            out[(jb + r) * HID + h*HD + dt*16 + lr] = acc[mt][r];
    }
}

extern "C" void kernel_launch(void* const* d_in, const int* in_sizes, int n_in,
                              void* d_out, int out_size, void* d_ws, size_t ws_size,
                              hipStream_t stream) {
    const float* in1 = (const float*)d_in[0];
    const float* in2 = (const float*)d_in[1];
    const float* Wq  = (const float*)d_in[2];
    const float* bq  = (const float*)d_in[3];
    const float* Wk  = (const float*)d_in[4];
    const float* bk  = (const float*)d_in[5];
    const float* Wv  = (const float*)d_in[6];
    const float* bv  = (const float*)d_in[7];
    float* out = (float*)d_out;

    float* ws   = (float*)d_ws;
    float* qbuf = ws;                       // 240*4096 f32
    float* kbuf = qbuf + SEQ*HID;           // 240*4096 f32
    float* vt   = kbuf + SEQ*HID;           // 4096*240 f32 (transposed V)
    float* pt   = vt + HID*SEQ;             // 16*240*240 f32 (transposed P)
    // total ws: ~14.8 MB

    qkv_kernel<<<dim3(64, 3), 256, 0, stream>>>(in1, in2, Wq, bq, Wk, bk, Wv, bv,
                                                qbuf, kbuf, vt);
    scores_kernel<<<dim3(15, 16), 64, 0, stream>>>(qbuf, kbuf, pt);
    pv_kernel<<<dim3(16, 16), 64, 0, stream>>>(pt, vt, out);
}

// Round 2
// 202.404 us; speedup vs baseline: 1.7827x; 1.7827x over previous
//
#include <hip/hip_runtime.h>
#include <hip/hip_bf16.h>

#define SEQ 240
#define HID 4096
#define NH 16
#define HD 256

typedef float f32x4 __attribute__((ext_vector_type(4)));
typedef short s16x8 __attribute__((ext_vector_type(8)));

__device__ __forceinline__ short f2bf(float f) {
    unsigned u = __builtin_bit_cast(unsigned, f);
    unsigned r = u + 0x7FFFu + ((u >> 16) & 1u);
    return (short)(r >> 16);
}

__device__ __forceinline__ s16x8 cvt8(float4 a, float4 b) {
    s16x8 r;
    r[0] = f2bf(a.x); r[1] = f2bf(a.y); r[2] = f2bf(a.z); r[3] = f2bf(a.w);
    r[4] = f2bf(b.x); r[5] = f2bf(b.y); r[6] = f2bf(b.z); r[7] = f2bf(b.w);
    return r;
}

// ---------------------------------------------------------------------------
// Kernel 0: convert inputs f32[240][4096] -> bf16 [256][4096], rows >=240 = 0
// ---------------------------------------------------------------------------
__global__ __launch_bounds__(256) void cvt_kernel(
    const float* __restrict__ in1, const float* __restrict__ in2,
    short* __restrict__ A1, short* __restrict__ A2)
{
    const int i = blockIdx.x * 256 + threadIdx.x;   // chunk of 8 elems
    const float* __restrict__ src = blockIdx.y ? in2 : in1;
    short* __restrict__ dst = blockIdx.y ? A2 : A1;
    const int r = i >> 9;            // 4096/8 = 512 chunks per row
    const int c = (i & 511) * 8;
    s16x8 v = (s16x8){0,0,0,0,0,0,0,0};
    if (r < SEQ) {
        float4 a = *(const float4*)&src[(size_t)r * HID + c];
        float4 b = *(const float4*)&src[(size_t)r * HID + c + 4];
        v = cvt8(a, b);
    }
    *(s16x8*)&dst[(size_t)r * HID + c] = v;
}

// ---------------------------------------------------------------------------
// Kernel 1: QKV gemm partials.  BM=256 (all rows), BN=128, BK=64, split-K.
// grid (32, 3, KS).  4 waves, per-wave tile 128x64 (acc[8][4]).
// LDS XOR-swizzled: short-index = row*64 + ((col8*8) ^ ((row&7)<<3)).
// ---------------------------------------------------------------------------
__global__ __launch_bounds__(256) void qkv_gemm(
    const short* __restrict__ A1, const short* __restrict__ A2,
    const float* __restrict__ Wq, const float* __restrict__ Wk,
    const float* __restrict__ Wv,
    float* __restrict__ pbuf, int KC)
{
    const int g  = blockIdx.y;
    const int z  = blockIdx.z;
    const int nb = blockIdx.x * 128;
    const short* __restrict__ A = (g == 0) ? A1 : A2;
    const float* __restrict__ W = (g == 0) ? Wq : (g == 1) ? Wk : Wv;

    const int tid  = threadIdx.x;
    const int lane = tid & 63;
    const int wave = tid >> 6;
    const int wm   = wave >> 1;   // 0..1 -> rows wm*128
    const int wn   = wave & 1;    // 0..1 -> cols wn*64
    const int lr   = lane & 15;
    const int lg   = lane >> 4;

    __shared__ short As[256 * 64];   // 32 KB
    __shared__ short Bs[128 * 64];   // 16 KB

    f32x4 acc[8][4];
    #pragma unroll
    for (int m = 0; m < 8; ++m)
        #pragma unroll
        for (int n = 0; n < 4; ++n)
            acc[m][n] = (f32x4){0.f, 0.f, 0.f, 0.f};

    const int trow = tid >> 3;   // 0..31
    const int tcol = tid & 7;    // 16B slot within a 128B row

    const int kbase = z * KC;
    for (int kk = 0; kk < KC; kk += 64) {
        const int k0 = kbase + kk;
        __syncthreads();
        // stage A: 256 rows x 64 bf16 (already bf16, zero-padded rows)
        #pragma unroll
        for (int p = 0; p < 8; ++p) {
            const int r = trow + p * 32;
            s16x8 v = *(const s16x8*)&A[(size_t)r * HID + k0 + tcol * 8];
            *(s16x8*)&As[r * 64 + ((tcol * 8) ^ ((r & 7) << 3))] = v;
        }
        // stage B: 128 rows x 64 f32 -> bf16
        #pragma unroll
        for (int p = 0; p < 4; ++p) {
            const int r = trow + p * 32;
            const float* src = &W[(size_t)(nb + r) * HID + k0 + tcol * 8];
            float4 b0 = *(const float4*)src;
            float4 b1 = *(const float4*)(src + 4);
            *(s16x8*)&Bs[r * 64 + ((tcol * 8) ^ ((r & 7) << 3))] = cvt8(b0, b1);
        }
        __syncthreads();

        #pragma unroll
        for (int ks = 0; ks < 2; ++ks) {
            const int colx = ks * 32 + lg * 8;
            s16x8 af[8], bf[4];
            #pragma unroll
            for (int m = 0; m < 8; ++m) {
                const int r = wm * 128 + m * 16 + lr;
                af[m] = *(const s16x8*)&As[r * 64 + (colx ^ ((r & 7) << 3))];
            }
            #pragma unroll
            for (int n = 0; n < 4; ++n) {
                const int r = wn * 64 + n * 16 + lr;
                bf[n] = *(const s16x8*)&Bs[r * 64 + (colx ^ ((r & 7) << 3))];
            }
            #pragma unroll
            for (int m = 0; m < 8; ++m)
                #pragma unroll
                for (int n = 0; n < 4; ++n)
                    acc[m][n] = __builtin_amdgcn_mfma_f32_16x16x32_bf16(af[m], bf[n], acc[m][n], 0, 0, 0);
        }
    }

    // store partial slab (no bias here)
    float* pout = pbuf + (size_t)(z * 3 + g) * SEQ * HID;
    #pragma unroll
    for (int m = 0; m < 8; ++m) {
        const int row0 = wm * 128 + m * 16 + lg * 4;
        if (row0 >= SEQ) continue;   // SEQ % 4 == 0, clean
        #pragma unroll
        for (int n = 0; n < 4; ++n) {
            const int col = nb + wn * 64 + n * 16 + lr;
            #pragma unroll
            for (int r = 0; r < 4; ++r)
                pout[(size_t)(row0 + r) * HID + col] = acc[m][n][r];
        }
    }
}

// ---------------------------------------------------------------------------
// Kernel 2: reduce split-K partials + bias -> qbuf/kbuf/vbuf (row-major f32)
// ---------------------------------------------------------------------------
__global__ __launch_bounds__(256) void reduce_kernel(
    const float* __restrict__ pbuf,
    const float* __restrict__ bq, const float* __restrict__ bk,
    const float* __restrict__ bv,
    float* __restrict__ qbuf, float* __restrict__ kbuf, float* __restrict__ vbuf,
    int KS)
{
    const int i = blockIdx.x * 256 + threadIdx.x;   // float4 index
    const int per = SEQ * HID / 4;                  // 245760 per g
    const int g = i / per;
    const int rem = i - g * per;
    f32x4 s = (f32x4){0.f, 0.f, 0.f, 0.f};
    for (int zz = 0; zz < KS; ++zz) {
        f32x4 v = *(const f32x4*)&pbuf[(size_t)(zz * 3 + g) * SEQ * HID + (size_t)rem * 4];
        s += v;
    }
    const int n = (rem * 4) & (HID - 1);
    const float* bias = (g == 0) ? bq : (g == 1) ? bk : bv;
    s += *(const f32x4*)&bias[n];
    float* ob = (g == 0) ? qbuf : (g == 1) ? kbuf : vbuf;
    *(f32x4*)&ob[(size_t)rem * 4] = s;
}

// ---------------------------------------------------------------------------
// Kernel 3: transpose vbuf[240][4096] -> vt[4096][240]
// ---------------------------------------------------------------------------
__global__ __launch_bounds__(256) void transpose_kernel(
    const float* __restrict__ vbuf, float* __restrict__ vt)
{
    __shared__ float tile[64][65];
    const int n0 = blockIdx.x * 64;
    const int m0 = blockIdx.y * 64;
    const int t  = threadIdx.x;
    const int tr = t >> 4, tc = t & 15;

    #pragma unroll
    for (int p = 0; p < 4; ++p) {
        const int ml = tr + p * 16;
        const int m  = m0 + ml;
        float4 v = make_float4(0.f, 0.f, 0.f, 0.f);
        if (m < SEQ) v = *(const float4*)&vbuf[(size_t)m * HID + n0 + tc * 4];
        tile[ml][tc * 4 + 0] = v.x;
        tile[ml][tc * 4 + 1] = v.y;
        tile[ml][tc * 4 + 2] = v.z;
        tile[ml][tc * 4 + 3] = v.w;
    }
    __syncthreads();
    #pragma unroll
    for (int p = 0; p < 4; ++p) {
        const int nl = tr + p * 16;
        const int m  = m0 + tc * 4;
        if (m < SEQ) {
            float4 o = make_float4(tile[tc*4+0][nl], tile[tc*4+1][nl],
                                   tile[tc*4+2][nl], tile[tc*4+3][nl]);
            *(float4*)&vt[(size_t)(n0 + nl) * SEQ + m] = o;
        }
    }
}

// ---------------------------------------------------------------------------
// Kernel 4: scores + row softmax.  P stored TRANSPOSED: pt[h][j][i].
// ---------------------------------------------------------------------------
__global__ __launch_bounds__(64) void scores_kernel(
    const float* __restrict__ qbuf, const float* __restrict__ kbuf,
    float* __restrict__ pt)
{
    const int it   = blockIdx.x;     // 0..14
    const int h    = blockIdx.y;     // 0..15
    const int lane = threadIdx.x;
    const int lr   = lane & 15;
    const int lg   = lane >> 4;

    f32x4 acc[15];
    #pragma unroll
    for (int j = 0; j < 15; ++j) acc[j] = (f32x4){0.f, 0.f, 0.f, 0.f};

    const int ib = it * 16;
    const float* qrow = &qbuf[(ib + lr) * HID + h * HD + lg * 8];

    for (int d0 = 0; d0 < HD; d0 += 32) {
        float4 a0 = *(const float4*)&qrow[d0];
        float4 a1 = *(const float4*)&qrow[d0 + 4];
        s16x8 afr = cvt8(a0, a1);
        #pragma unroll
        for (int jt = 0; jt < 15; ++jt) {
            const float* krow = &kbuf[(jt*16 + lr) * HID + h * HD + d0 + lg * 8];
            float4 b0 = *(const float4*)&krow[0];
            float4 b1 = *(const float4*)&krow[4];
            acc[jt] = __builtin_amdgcn_mfma_f32_16x16x32_bf16(afr, cvt8(b0, b1), acc[jt], 0, 0, 0);
        }
    }

    const float sc = 0.0625f;  // 1/sqrt(256)
    #pragma unroll
    for (int jt = 0; jt < 15; ++jt) acc[jt] *= sc;

    #pragma unroll
    for (int r = 0; r < 4; ++r) {
        float mx = acc[0][r];
        #pragma unroll
        for (int jt = 1; jt < 15; ++jt) mx = fmaxf(mx, acc[jt][r]);
        #pragma unroll
        for (int s = 1; s < 16; s <<= 1) mx = fmaxf(mx, __shfl_xor(mx, s, 64));
        float sum = 0.f;
        #pragma unroll
        for (int jt = 0; jt < 15; ++jt) {
            float e = expf(acc[jt][r] - mx);
            acc[jt][r] = e;
            sum += e;
        }
        #pragma unroll
        for (int s = 1; s < 16; s <<= 1) sum += __shfl_xor(sum, s, 64);
        float inv = 1.f / sum;
        #pragma unroll
        for (int jt = 0; jt < 15; ++jt) acc[jt][r] *= inv;
    }

    #pragma unroll
    for (int jt = 0; jt < 15; ++jt) {
        const int j = jt*16 + lr;
        float4 o = make_float4(acc[jt][0], acc[jt][1], acc[jt][2], acc[jt][3]);
        *(float4*)&pt[(h*SEQ + j)*SEQ + ib + lg*4] = o;
    }
}

// ---------------------------------------------------------------------------
// Kernel 5: O = P^T V per head (NT, K=i over 240 padded to 256)
// ---------------------------------------------------------------------------
__global__ __launch_bounds__(64) void pv_kernel(
    const float* __restrict__ pt, const float* __restrict__ vtbuf,
    float* __restrict__ out)
{
    const int dt   = blockIdx.x;     // 0..15
    const int h    = blockIdx.y;
    const int lane = threadIdx.x;
    const int lr   = lane & 15;
    const int lg   = lane >> 4;

    f32x4 acc[15];
    #pragma unroll
    for (int m = 0; m < 15; ++m) acc[m] = (f32x4){0.f, 0.f, 0.f, 0.f};

    const float* vrow  = &vtbuf[(h*HD + dt*16 + lr) * SEQ + lg*8];
    const float* pbase = &pt[h*SEQ*SEQ];

    for (int i0 = 0; i0 < 256; i0 += 32) {
        const bool ok = (i0 + lg*8) < SEQ;
        s16x8 bfr = (s16x8){0,0,0,0,0,0,0,0};
        if (ok) {
            float4 b0 = *(const float4*)&vrow[i0];
            float4 b1 = *(const float4*)&vrow[i0 + 4];
            bfr = cvt8(b0, b1);
        }
        #pragma unroll
        for (int mt = 0; mt < 15; ++mt) {
            s16x8 afr = (s16x8){0,0,0,0,0,0,0,0};
            if (ok) {
                const float* prow = &pbase[(mt*16 + lr)*SEQ + i0 + lg*8];
                float4 a0 = *(const float4*)&prow[0];
                float4 a1 = *(const float4*)&prow[4];
                afr = cvt8(a0, a1);
            }
            acc[mt] = __builtin_amdgcn_mfma_f32_16x16x32_bf16(afr, bfr, acc[mt], 0, 0, 0);
        }
    }

    #pragma unroll
    for (int mt = 0; mt < 15; ++mt) {
        const int jb = mt*16 + lg*4;
        #pragma unroll
        for (int r = 0; r < 4; ++r)
            out[(jb + r) * HID + h*HD + dt*16 + lr] = acc[mt][r];
    }
}

extern "C" void kernel_launch(void* const* d_in, const int* in_sizes, int n_in,
                              void* d_out, int out_size, void* d_ws, size_t ws_size,
                              hipStream_t stream) {
    const float* in1 = (const float*)d_in[0];
    const float* in2 = (const float*)d_in[1];
    const float* Wq  = (const float*)d_in[2];
    const float* bq  = (const float*)d_in[3];
    const float* Wk  = (const float*)d_in[4];
    const float* bk  = (const float*)d_in[5];
    const float* Wv  = (const float*)d_in[6];
    const float* bv  = (const float*)d_in[7];
    float* out = (float*)d_out;

    char* w = (char*)d_ws;
    const size_t szA  = (size_t)256 * HID * sizeof(short);     // 2 MB
    const size_t szQ  = (size_t)SEQ * HID * sizeof(float);     // 3.93 MB
    const size_t szPT = (size_t)NH * SEQ * SEQ * sizeof(float);// 3.69 MB
    const size_t szP1 = (size_t)3 * SEQ * HID * sizeof(float); // 11.8 MB per z

    short* A1   = (short*)w;            w += szA;
    short* A2   = (short*)w;            w += szA;
    float* qbuf = (float*)w;            w += szQ;
    float* kbuf = (float*)w;            w += szQ;
    float* vbuf = (float*)w;            w += szQ;
    float* vt   = (float*)w;            w += szQ;
    float* pt   = (float*)w;            w += szPT;
    float* pbuf = (float*)w;
    const size_t fixed = (size_t)(w - (char*)d_ws);

    int KS = 1;
    if (fixed + 4 * szP1 <= ws_size)      KS = 4;
    else if (fixed + 2 * szP1 <= ws_size) KS = 2;
    const int KC = HID / KS;

    cvt_kernel<<<dim3(512, 2), 256, 0, stream>>>(in1, in2, A1, A2);
    qkv_gemm<<<dim3(32, 3, KS), 256, 0, stream>>>(A1, A2, Wq, Wk, Wv, pbuf, KC);
    reduce_kernel<<<2880, 256, 0, stream>>>(pbuf, bq, bk, bv, qbuf, kbuf, vbuf, KS);
    transpose_kernel<<<dim3(64, 4), 256, 0, stream>>>(vbuf, vt);
    scores_kernel<<<dim3(15, 16), 64, 0, stream>>>(qbuf, kbuf, pt);
    pv_kernel<<<dim3(16, 16), 64, 0, stream>>>(pt, vt, out);
}

// Round 4
// 95.657 us; speedup vs baseline: 3.7721x; 2.1159x over previous
//
#include <hip/hip_runtime.h>
#include <hip/hip_bf16.h>

#define SEQ 240
#define HID 4096
#define NH 16
#define HD 256

typedef float f32x4 __attribute__((ext_vector_type(4)));
typedef short s16x8 __attribute__((ext_vector_type(8)));
typedef short s16x4 __attribute__((ext_vector_type(4)));

__device__ __forceinline__ short f2bf(float f) {
    unsigned u = __builtin_bit_cast(unsigned, f);
    unsigned r = u + 0x7FFFu + ((u >> 16) & 1u);
    return (short)(r >> 16);
}

__device__ __forceinline__ s16x8 cvt8(float4 a, float4 b) {
    s16x8 r;
    r[0] = f2bf(a.x); r[1] = f2bf(a.y); r[2] = f2bf(a.z); r[3] = f2bf(a.w);
    r[4] = f2bf(b.x); r[5] = f2bf(b.y); r[6] = f2bf(b.z); r[7] = f2bf(b.w);
    return r;
}

// ---------------------------------------------------------------------------
// Kernel 0: convert inputs f32[240][4096] -> bf16 [256][4096], rows >=240 = 0
// ---------------------------------------------------------------------------
__global__ __launch_bounds__(256) void cvt_kernel(
    const float* __restrict__ in1, const float* __restrict__ in2,
    short* __restrict__ A1, short* __restrict__ A2)
{
    const int i = blockIdx.x * 256 + threadIdx.x;   // chunk of 8 elems
    const float* __restrict__ src = blockIdx.y ? in2 : in1;
    short* __restrict__ dst = blockIdx.y ? A2 : A1;
    const int r = i >> 9;
    const int c = (i & 511) * 8;
    s16x8 v = (s16x8){0,0,0,0,0,0,0,0};
    if (r < SEQ) {
        float4 a = *(const float4*)&src[(size_t)r * HID + c];
        float4 b = *(const float4*)&src[(size_t)r * HID + c + 4];
        v = cvt8(a, b);
    }
    *(s16x8*)&dst[(size_t)r * HID + c] = v;
}

// ---------------------------------------------------------------------------
// Kernel 1: QKV gemm partials, 2-phase reg-staged pipeline.
// BM=256, BN=64, BK=64, double-buffered LDS (80KB), grid (64, 3, KS).
// 4 waves as 2m x 2n, per-wave tile 128x32 (acc[8][2]).
// A staging: 256 threads x 8 chunks (tid>>3 rows, tid&7 col-slots) = FULL
// 256x64 tile.  (Round-3 bug: 4 chunks only staged cols 0..31.)
// v (g==2) partials stored TRANSPOSED: pvt[z][n][m].
// ---------------------------------------------------------------------------
__global__ __launch_bounds__(256) void qkv_gemm(
    const short* __restrict__ A1, const short* __restrict__ A2,
    const float* __restrict__ Wq, const float* __restrict__ Wk,
    const float* __restrict__ Wv,
    float* __restrict__ pqk, float* __restrict__ pvt, int KC)
{
    const int g  = blockIdx.y;
    const int z  = blockIdx.z;
    const int nb = blockIdx.x * 64;
    const short* __restrict__ A = (g == 0) ? A1 : A2;
    const float* __restrict__ W = (g == 0) ? Wq : (g == 1) ? Wk : Wv;

    const int tid  = threadIdx.x;
    const int lane = tid & 63;
    const int wave = tid >> 6;
    const int wm   = wave >> 1;
    const int wn   = wave & 1;
    const int lr   = lane & 15;
    const int lg   = lane >> 4;

    __shared__ short As[2][256 * 64];   // 2 x 32 KB
    __shared__ short Bs[2][64 * 64];    // 2 x  8 KB

    f32x4 acc[8][2];
    #pragma unroll
    for (int m = 0; m < 8; ++m)
        #pragma unroll
        for (int n = 0; n < 2; ++n)
            acc[m][n] = (f32x4){0.f, 0.f, 0.f, 0.f};

    const int arow = tid >> 3;   // 0..31 (+32p, p<8)
    const int asl  = tid & 7;    // 16B slot within 128B row (all 64 cols)
    const int brow = tid >> 3;   // 0..31 (+32q, q<2)
    const int bsl  = tid & 7;

    s16x8 ra[8];
    float4 rb0[2], rb1[2];

    const int kbase = z * KC;
    const int NIT = KC / 64;

    auto LOADT = [&](int k0) {
        #pragma unroll
        for (int p = 0; p < 8; ++p)
            ra[p] = *(const s16x8*)&A[(size_t)(arow + p * 32) * HID + k0 + asl * 8];
        #pragma unroll
        for (int q = 0; q < 2; ++q) {
            const float* src = &W[(size_t)(nb + brow + q * 32) * HID + k0 + bsl * 8];
            rb0[q] = *(const float4*)src;
            rb1[q] = *(const float4*)(src + 4);
        }
    };
    auto STORET = [&](int b) {
        #pragma unroll
        for (int p = 0; p < 8; ++p) {
            const int r = arow + p * 32;
            *(s16x8*)&As[b][r * 64 + ((asl * 8) ^ ((r & 7) << 3))] = ra[p];
        }
        #pragma unroll
        for (int q = 0; q < 2; ++q) {
            const int r = brow + q * 32;
            *(s16x8*)&Bs[b][r * 64 + ((bsl * 8) ^ ((r & 7) << 3))] = cvt8(rb0[q], rb1[q]);
        }
    };

    LOADT(kbase);
    STORET(0);
    __syncthreads();

    for (int it = 0; it < NIT; ++it) {
        if (it + 1 < NIT) LOADT(kbase + (it + 1) * 64);   // issue early, in flight across compute
        const int b = it & 1;
        #pragma unroll
        for (int ks = 0; ks < 2; ++ks) {
            const int colx = ks * 32 + lg * 8;
            s16x8 af[8], bf[2];
            #pragma unroll
            for (int m = 0; m < 8; ++m) {
                const int r = wm * 128 + m * 16 + lr;
                af[m] = *(const s16x8*)&As[b][r * 64 + (colx ^ ((r & 7) << 3))];
            }
            #pragma unroll
            for (int n = 0; n < 2; ++n) {
                const int r = wn * 32 + n * 16 + lr;
                bf[n] = *(const s16x8*)&Bs[b][r * 64 + (colx ^ ((r & 7) << 3))];
            }
            #pragma unroll
            for (int m = 0; m < 8; ++m)
                #pragma unroll
                for (int n = 0; n < 2; ++n)
                    acc[m][n] = __builtin_amdgcn_mfma_f32_16x16x32_bf16(af[m], bf[n], acc[m][n], 0, 0, 0);
        }
        __syncthreads();                       // all reads of buf b done
        if (it + 1 < NIT) {
            STORET((it + 1) & 1);
            __syncthreads();                   // writes visible before next compute
        }
    }

    if (g == 2) {
        // transposed partial store: pvt[z][n][m]
        float* pout = pvt + (size_t)z * HID * SEQ;
        #pragma unroll
        for (int m = 0; m < 8; ++m) {
            const int row0 = wm * 128 + m * 16 + lg * 4;
            if (row0 >= SEQ) continue;
            #pragma unroll
            for (int n = 0; n < 2; ++n) {
                const int col = nb + wn * 32 + n * 16 + lr;
                float4 o = make_float4(acc[m][n][0], acc[m][n][1], acc[m][n][2], acc[m][n][3]);
                *(float4*)&pout[(size_t)col * SEQ + row0] = o;
            }
        }
    } else {
        float* pout = pqk + (size_t)(z * 2 + g) * SEQ * HID;
        #pragma unroll
        for (int m = 0; m < 8; ++m) {
            const int row0 = wm * 128 + m * 16 + lg * 4;
            if (row0 >= SEQ) continue;
            #pragma unroll
            for (int n = 0; n < 2; ++n) {
                const int col = nb + wn * 32 + n * 16 + lr;
                #pragma unroll
                for (int r = 0; r < 4; ++r)
                    pout[(size_t)(row0 + r) * HID + col] = acc[m][n][r];
            }
        }
    }
}

// ---------------------------------------------------------------------------
// Kernel 2: reduce q/k partials + bias -> bf16 row-major
// ---------------------------------------------------------------------------
__global__ __launch_bounds__(256) void reduce_qk(
    const float* __restrict__ pqk,
    const float* __restrict__ bq, const float* __restrict__ bk,
    short* __restrict__ qb, short* __restrict__ kb, int KS)
{
    const int g   = blockIdx.y;
    const int idx = blockIdx.x * 256 + threadIdx.x;   // f32x4 index
    f32x4 s = (f32x4){0.f, 0.f, 0.f, 0.f};
    for (int z = 0; z < KS; ++z)
        s += *(const f32x4*)&pqk[(size_t)(z * 2 + g) * SEQ * HID + (size_t)idx * 4];
    const int n = (idx * 4) & (HID - 1);
    const float* bias = g ? bk : bq;
    s += *(const f32x4*)&bias[n];
    short* ob = g ? kb : qb;
    s16x4 o = (s16x4){f2bf(s[0]), f2bf(s[1]), f2bf(s[2]), f2bf(s[3])};
    *(s16x4*)&ob[(size_t)idx * 4] = o;
}

// ---------------------------------------------------------------------------
// Kernel 3: reduce transposed v partials + bias -> vtb bf16 [4096][240]
// ---------------------------------------------------------------------------
__global__ __launch_bounds__(256) void reduce_v(
    const float* __restrict__ pvt, const float* __restrict__ bv,
    short* __restrict__ vtb, int KS)
{
    const int idx = blockIdx.x * 256 + threadIdx.x;   // f32x4 index over [4096][240]
    f32x4 s = (f32x4){0.f, 0.f, 0.f, 0.f};
    for (int z = 0; z < KS; ++z)
        s += *(const f32x4*)&pvt[(size_t)z * HID * SEQ + (size_t)idx * 4];
    const int n = idx / 60;                           // 60 f32x4 per 240-row
    const float b = bv[n];
    s16x4 o = (s16x4){f2bf(s[0] + b), f2bf(s[1] + b), f2bf(s[2] + b), f2bf(s[3] + b)};
    *(s16x4*)&vtb[(size_t)idx * 4] = o;
}

// ---------------------------------------------------------------------------
// Kernel 4: scores + softmax.  4 waves/block, jt-split, LDS cross-wave
// softmax combine.  P^T stored bf16: ptb[h][j][i].
// ---------------------------------------------------------------------------
__global__ __launch_bounds__(256) void scores_kernel(
    const short* __restrict__ qb, const short* __restrict__ kb,
    short* __restrict__ ptb)
{
    const int it   = blockIdx.x;     // 0..14
    const int h    = blockIdx.y;     // 0..15
    const int tid  = threadIdx.x;
    const int lane = tid & 63;
    const int w    = tid >> 6;
    const int lr   = lane & 15;
    const int lg   = lane >> 4;
    const int jt0  = w * 4;
    const int NJT  = (w < 3) ? 4 : 3;

    __shared__ float redmax[4][16];
    __shared__ float redsum[4][16];

    f32x4 acc[4];
    #pragma unroll
    for (int j = 0; j < 4; ++j) acc[j] = (f32x4){0.f, 0.f, 0.f, 0.f};

    const int ib = it * 16;
    const short* qrow = &qb[(size_t)(ib + lr) * HID + h * HD + lg * 8];

    for (int d0 = 0; d0 < HD; d0 += 32) {
        s16x8 afr = *(const s16x8*)&qrow[d0];
        #pragma unroll
        for (int j = 0; j < 4; ++j) {
            if (j < NJT) {
                s16x8 bfr = *(const s16x8*)&kb[(size_t)((jt0 + j) * 16 + lr) * HID + h * HD + d0 + lg * 8];
                acc[j] = __builtin_amdgcn_mfma_f32_16x16x32_bf16(afr, bfr, acc[j], 0, 0, 0);
            }
        }
    }

    const float sc = 0.0625f;
    #pragma unroll
    for (int j = 0; j < 4; ++j) acc[j] *= sc;

    // phase 1: wave-local max per i, publish
    #pragma unroll
    for (int r = 0; r < 4; ++r) {
        float mx = -1e30f;
        #pragma unroll
        for (int j = 0; j < 4; ++j) if (j < NJT) mx = fmaxf(mx, acc[j][r]);
        #pragma unroll
        for (int s = 1; s < 16; s <<= 1) mx = fmaxf(mx, __shfl_xor(mx, s, 64));
        if (lr == 0) redmax[w][lg * 4 + r] = mx;
    }
    __syncthreads();
    // phase 2: global max, exp, wave-local sum, publish
    #pragma unroll
    for (int r = 0; r < 4; ++r) {
        const int i = lg * 4 + r;
        float mx = fmaxf(fmaxf(redmax[0][i], redmax[1][i]),
                         fmaxf(redmax[2][i], redmax[3][i]));
        float sum = 0.f;
        #pragma unroll
        for (int j = 0; j < 4; ++j) {
            if (j < NJT) {
                float e = expf(acc[j][r] - mx);
                acc[j][r] = e;
                sum += e;
            }
        }
        #pragma unroll
        for (int s = 1; s < 16; s <<= 1) sum += __shfl_xor(sum, s, 64);
        if (lr == 0) redsum[w][i] = sum;
    }
    __syncthreads();
    // phase 3: normalize + store bf16 (4 consecutive i per lane)
    #pragma unroll
    for (int r = 0; r < 4; ++r) {
        const int i = lg * 4 + r;
        const float inv = 1.f / (redsum[0][i] + redsum[1][i] + redsum[2][i] + redsum[3][i]);
        #pragma unroll
        for (int j = 0; j < 4; ++j) if (j < NJT) acc[j][r] *= inv;
    }
    #pragma unroll
    for (int j = 0; j < 4; ++j) {
        if (j < NJT) {
            const int jj = (jt0 + j) * 16 + lr;
            s16x4 o = (s16x4){f2bf(acc[j][0]), f2bf(acc[j][1]), f2bf(acc[j][2]), f2bf(acc[j][3])};
            *(s16x4*)&ptb[(size_t)(h * SEQ + jj) * SEQ + ib + lg * 4] = o;
        }
    }
}

// ---------------------------------------------------------------------------
// Kernel 5: O = P^T V per head, 4 waves/block jt-split, all-bf16 inputs.
// ---------------------------------------------------------------------------
__global__ __launch_bounds__(256) void pv_kernel(
    const short* __restrict__ ptb, const short* __restrict__ vtb,
    float* __restrict__ out)
{
    const int dt   = blockIdx.x;     // 0..15
    const int h    = blockIdx.y;
    const int tid  = threadIdx.x;
    const int lane = tid & 63;
    const int w    = tid >> 6;
    const int lr   = lane & 15;
    const int lg   = lane >> 4;
    const int NJT  = (w < 3) ? 4 : 3;

    f32x4 acc[4];
    #pragma unroll
    for (int j = 0; j < 4; ++j) acc[j] = (f32x4){0.f, 0.f, 0.f, 0.f};

    const short* vrow = &vtb[(size_t)(h * HD + dt * 16 + lr) * SEQ + lg * 8];

    for (int i0 = 0; i0 < 256; i0 += 32) {
        const bool ok = (i0 + lg * 8) < SEQ;
        s16x8 bfr = (s16x8){0,0,0,0,0,0,0,0};
        if (ok) bfr = *(const s16x8*)&vrow[i0];
        #pragma unroll
        for (int j = 0; j < 4; ++j) {
            if (j < NJT) {
                const int jt = w + j * 4;
                s16x8 afr = (s16x8){0,0,0,0,0,0,0,0};
                if (ok) afr = *(const s16x8*)&ptb[(size_t)(h * SEQ + jt * 16 + lr) * SEQ + i0 + lg * 8];
                acc[j] = __builtin_amdgcn_mfma_f32_16x16x32_bf16(afr, bfr, acc[j], 0, 0, 0);
            }
        }
    }

    #pragma unroll
    for (int j = 0; j < 4; ++j) {
        if (j < NJT) {
            const int jt = w + j * 4;
            #pragma unroll
            for (int r = 0; r < 4; ++r)
                out[(size_t)(jt * 16 + lg * 4 + r) * HID + h * HD + dt * 16 + lr] = acc[j][r];
        }
    }
}

extern "C" void kernel_launch(void* const* d_in, const int* in_sizes, int n_in,
                              void* d_out, int out_size, void* d_ws, size_t ws_size,
                              hipStream_t stream) {
    const float* in1 = (const float*)d_in[0];
    const float* in2 = (const float*)d_in[1];
    const float* Wq  = (const float*)d_in[2];
    const float* bq  = (const float*)d_in[3];
    const float* Wk  = (const float*)d_in[4];
    const float* bk  = (const float*)d_in[5];
    const float* Wv  = (const float*)d_in[6];
    const float* bv  = (const float*)d_in[7];
    float* out = (float*)d_out;

    char* w = (char*)d_ws;
    short* A1  = (short*)w;  w += (size_t)256 * HID * 2;        // 2 MB
    short* A2  = (short*)w;  w += (size_t)256 * HID * 2;        // 2 MB
    short* qb  = (short*)w;  w += (size_t)SEQ * HID * 2;        // 1.97 MB
    short* kb  = (short*)w;  w += (size_t)SEQ * HID * 2;
    short* vtb = (short*)w;  w += (size_t)HID * SEQ * 2;
    short* ptb = (short*)w;  w += (size_t)NH * SEQ * SEQ * 2;   // 1.84 MB
    float* pqk = (float*)w;
    const size_t fixed  = (size_t)(w - (char*)d_ws);
    const size_t perKS  = ((size_t)2 * SEQ * HID + (size_t)HID * SEQ) * sizeof(float); // 11.8 MB

    int KS = 1;
    if (fixed + 4 * perKS <= ws_size)      KS = 4;
    else if (fixed + 2 * perKS <= ws_size) KS = 2;
    const int KC = HID / KS;
    float* pvt = pqk + (size_t)KS * 2 * SEQ * HID;

    cvt_kernel<<<dim3(512, 2), 256, 0, stream>>>(in1, in2, A1, A2);
    qkv_gemm<<<dim3(64, 3, KS), 256, 0, stream>>>(A1, A2, Wq, Wk, Wv, pqk, pvt, KC);
    reduce_qk<<<dim3(960, 2), 256, 0, stream>>>(pqk, bq, bk, qb, kb, KS);
    reduce_v<<<960, 256, 0, stream>>>(pvt, bv, vtb, KS);
    scores_kernel<<<dim3(15, 16), 256, 0, stream>>>(qb, kb, ptb);
    pv_kernel<<<dim3(16, 16), 256, 0, stream>>>(ptb, vtb, out);
}